// Round 3
// baseline (1314.980 us; speedup 1.0000x reference)
//
#include <hip/hip_runtime.h>
#include <cstdint>
#include <cmath>

#define S_LEN 4096
#define H_DIM 2304
#define NQH   8
#define NKVH  4
#define HDIM  256
#define INTER 9216
#define QKV_N 4096   // (NQ + 2*NKV) * HD
#define QH    2048   // NQ*HD
#define KVH   1024   // NKV*HD

typedef __attribute__((ext_vector_type(4))) float  f32x4;
typedef __attribute__((ext_vector_type(8))) __bf16 bf16x8;
typedef __attribute__((ext_vector_type(4))) __bf16 bf16x4;

__device__ __forceinline__ __bf16 f2bf(float f) {
  union { float f; unsigned u; } x; x.f = f;
  unsigned r = (x.u + 0x7fffu + ((x.u >> 16) & 1u)) >> 16;   // RNE
  union { unsigned short s; __bf16 b; } y; y.s = (unsigned short)r;
  return y.b;
}

// async global->LDS, 16B per lane. LDS dest must be wave-uniform base + lane*16.
__device__ __forceinline__ void g2l16(const void* g, void* l) {
  __builtin_amdgcn_global_load_lds(
      (__attribute__((address_space(1))) void*)(uintptr_t)g,
      (__attribute__((address_space(3))) void*)(uint32_t)(uintptr_t)l, 16, 0, 0);
}

__device__ __forceinline__ float block_sum(float v, float* sbuf) {
  #pragma unroll
  for (int o = 32; o > 0; o >>= 1) v += __shfl_xor(v, o);
  __syncthreads();
  if ((threadIdx.x & 63) == 0) sbuf[threadIdx.x >> 6] = v;
  __syncthreads();
  return sbuf[0] + sbuf[1] + sbuf[2] + sbuf[3];
}

// ------------- vectorized transpose: fp32 [K][N] -> bf16 [N][K] (64x64) -------
__global__ void conv_t64(const float* __restrict__ src, __bf16* __restrict__ dst,
                         int srcStride, int dstStride) {
  __shared__ float t[64 * 65];
  int tid = threadIdx.x;                 // 256
  long n0 = (long)blockIdx.x * 64, k0 = (long)blockIdx.y * 64;
  int tx = tid & 15;                     // 16 x f32x4 = 64 floats per row
  int ky = tid >> 4;                     // 0..15
  #pragma unroll
  for (int l = 0; l < 4; ++l) {
    int k = ky + l * 16;
    f32x4 v = *(const f32x4*)(src + (k0 + k) * srcStride + n0 + tx * 4);
    #pragma unroll
    for (int e = 0; e < 4; ++e) t[(tx * 4 + e) * 65 + k] = v[e];
  }
  __syncthreads();
  int ny = tid >> 2, kc = (tid & 3) * 16;
  bf16x8 a, b;
  #pragma unroll
  for (int i = 0; i < 8; ++i) a[i] = f2bf(t[ny * 65 + kc + i]);
  #pragma unroll
  for (int i = 0; i < 8; ++i) b[i] = f2bf(t[ny * 65 + kc + 8 + i]);
  __bf16* d = dst + (n0 + ny) * dstStride + k0 + kc;
  *(bf16x8*)d = a;
  *(bf16x8*)(d + 8) = b;
}

// gate/up interleave permutation (epilogue pairing of gemm8<1>)
__device__ __forceinline__ int gu_map(int n) {
  int t = n >> 7, w = (n >> 6) & 1, j = (n >> 4) & 3, c = n & 15;
  int a = t * 64 + w * 32 + ((j >> 1) << 4) + c;
  return (j & 1) ? (INTER + a) : a;
}

__global__ void conv_gu64(const float* __restrict__ src, __bf16* __restrict__ dst) {
  __shared__ float t[64 * 65];
  int tid = threadIdx.x;
  long n0 = (long)blockIdx.x * 64, k0 = (long)blockIdx.y * 64;
  int tx = tid & 15, ky = tid >> 4;
  int sc = gu_map((int)n0 + tx * 4);
  #pragma unroll
  for (int l = 0; l < 4; ++l) {
    int k = ky + l * 16;
    f32x4 v = *(const f32x4*)(src + (k0 + k) * (2 * INTER) + sc);
    #pragma unroll
    for (int e = 0; e < 4; ++e) t[(tx * 4 + e) * 65 + k] = v[e];
  }
  __syncthreads();
  int ny = tid >> 2, kc = (tid & 3) * 16;
  bf16x8 a, b;
  #pragma unroll
  for (int i = 0; i < 8; ++i) a[i] = f2bf(t[ny * 65 + kc + i]);
  #pragma unroll
  for (int i = 0; i < 8; ++i) b[i] = f2bf(t[ny * 65 + kc + 8 + i]);
  __bf16* d = dst + (n0 + ny) * H_DIM + k0 + kc;
  *(bf16x8*)d = a;
  *(bf16x8*)(d + 8) = b;
}

// ---------------- rmsnorm kernels (H = 2304 = 9*256) --------------------------
__global__ void rms_in_kernel(const float* __restrict__ x, const float* __restrict__ w,
                              __bf16* __restrict__ out) {
  __shared__ float sbuf[4];
  int row = blockIdx.x, tid = threadIdx.x;
  const float* xr = x + (long)row * H_DIM;
  float v[9]; float ss = 0.f;
  #pragma unroll
  for (int i = 0; i < 9; ++i) { v[i] = xr[tid + i * 256]; ss += v[i] * v[i]; }
  ss = block_sum(ss, sbuf);
  float inv = rsqrtf(ss * (1.0f / H_DIM) + 1e-6f);
  #pragma unroll
  for (int i = 0; i < 9; ++i)
    out[(long)row * H_DIM + tid + i * 256] = f2bf(v[i] * inv * (1.f + w[tid + i * 256]));
}

__global__ void rms_post_attn_kernel(const float* __restrict__ P, const float* __restrict__ hidden,
                                     const float* __restrict__ w_post, const float* __restrict__ w_pre,
                                     float* __restrict__ resid, __bf16* __restrict__ x2) {
  __shared__ float sbuf[4];
  int row = blockIdx.x, tid = threadIdx.x;
  const float* pr = P + (long)row * H_DIM;
  const float* hr = hidden + (long)row * H_DIM;
  float pv[9]; float ss = 0.f;
  #pragma unroll
  for (int i = 0; i < 9; ++i) { pv[i] = pr[tid + i * 256]; ss += pv[i] * pv[i]; }
  ss = block_sum(ss, sbuf);
  float inv = rsqrtf(ss * (1.0f / H_DIM) + 1e-6f);
  float rv[9]; float ss2 = 0.f;
  #pragma unroll
  for (int i = 0; i < 9; ++i) {
    int c = tid + i * 256;
    float hn = pv[i] * inv * (1.f + w_post[c]);
    rv[i] = hn + hr[c];
    resid[(long)row * H_DIM + c] = rv[i];
    ss2 += rv[i] * rv[i];
  }
  ss2 = block_sum(ss2, sbuf);
  float inv2 = rsqrtf(ss2 * (1.0f / H_DIM) + 1e-6f);
  #pragma unroll
  for (int i = 0; i < 9; ++i) {
    int c = tid + i * 256;
    x2[(long)row * H_DIM + c] = f2bf(rv[i] * inv2 * (1.f + w_pre[c]));
  }
}

__global__ void rms_final_kernel(const float* __restrict__ x, const float* __restrict__ w,
                                 float* __restrict__ out) {
  __shared__ float sbuf[4];
  int row = blockIdx.x, tid = threadIdx.x;
  const float* xr = x + (long)row * H_DIM;
  float v[9]; float ss = 0.f;
  #pragma unroll
  for (int i = 0; i < 9; ++i) { v[i] = xr[tid + i * 256]; ss += v[i] * v[i]; }
  ss = block_sum(ss, sbuf);
  float inv = rsqrtf(ss * (1.0f / H_DIM) + 1e-6f);
  #pragma unroll
  for (int i = 0; i < 9; ++i)
    out[(long)row * H_DIM + tid + i * 256] = v[i] * inv * (1.f + w[tid + i * 256]);
}

// ---------------- GEMM: C[M][N] = A[M][K](bf16) x B[N][K](bf16) ---------------
// 128x128 tile, 4 waves 2x2, BK=64, global_load_lds width 16, XOR chunk swizzle,
// bijective XCD swizzle. Used for Wo and down GEMMs.
template <int EPI>
__global__ void gemm_bt(const __bf16* __restrict__ A, const __bf16* __restrict__ B,
                        void* __restrict__ Cout, int K, int ldc) {
  __shared__ __bf16 As[128 * 64];
  __shared__ __bf16 Bs[128 * 64];
  int tid = threadIdx.x;
  int wave = tid >> 6, lane = tid & 63;
  int wm = wave >> 1, wn = wave & 1;
  int q4 = lane >> 4, l15 = lane & 15;

  int nwgx = gridDim.x;
  int nwg = nwgx * gridDim.y;
  int orig = blockIdx.y * nwgx + blockIdx.x;
  int qd = nwg >> 3, rm = nwg & 7;
  int xcd = orig & 7, idx = orig >> 3;
  int swz = (xcd < rm ? xcd * (qd + 1) : rm * (qd + 1) + (xcd - rm) * qd) + idx;
  long bm = (long)(swz / nwgx) * 128, bn = (long)(swz % nwgx) * 128;

  int r8 = tid >> 3;                         // 0..31
  int cs = (tid & 7) ^ (r8 & 7);
  const __bf16* Ag = A + (bm + r8) * K + cs * 8;
  const __bf16* Bg = B + (bn + r8) * K + cs * 8;
  __bf16* Asd = As + tid * 8;
  __bf16* Bsd = Bs + tid * 8;

  int moff[4], noff[4];
  #pragma unroll
  for (int i = 0; i < 4; ++i) {
    moff[i] = (wm * 64 + i * 16 + l15) * 64;
    noff[i] = (wn * 64 + i * 16 + l15) * 64;
  }
  int c0 = (q4 ^ (l15 & 7)) * 8;             // ks=0 element offset; ks=1: ^32
  f32x4 acc[4][4] = {};

  for (int k0 = 0; k0 < K; k0 += 64) {
    #pragma unroll
    for (int l = 0; l < 4; ++l) {
      g2l16(Ag + (long)(l * 32) * K, Asd + l * 2048);
      g2l16(Bg + (long)(l * 32) * K, Bsd + l * 2048);
    }
    Ag += 64; Bg += 64;
    __syncthreads();
    #pragma unroll
    for (int ks = 0; ks < 2; ++ks) {
      int cc = c0 ^ (ks * 32);
      bf16x8 af[4], bfv[4];
      #pragma unroll
      for (int i = 0; i < 4; ++i) af[i]  = *(const bf16x8*)(As + moff[i] + cc);
      #pragma unroll
      for (int j = 0; j < 4; ++j) bfv[j] = *(const bf16x8*)(Bs + noff[j] + cc);
      #pragma unroll
      for (int i = 0; i < 4; ++i)
        #pragma unroll
        for (int j = 0; j < 4; ++j)
          acc[i][j] = __builtin_amdgcn_mfma_f32_16x16x32_bf16(af[i], bfv[j], acc[i][j], 0, 0, 0);
    }
    __syncthreads();
  }

  if (EPI == 0) {
    float* C = (float*)Cout;
    #pragma unroll
    for (int i = 0; i < 4; ++i)
      #pragma unroll
      for (int r = 0; r < 4; ++r) {
        long m = bm + wm * 64 + i * 16 + q4 * 4 + r;
        #pragma unroll
        for (int j = 0; j < 4; ++j)
          C[m * ldc + bn + wn * 64 + j * 16 + l15] = acc[i][j][r];
      }
  } else {
    __bf16* C = (__bf16*)Cout;
    #pragma unroll
    for (int i = 0; i < 4; ++i)
      #pragma unroll
      for (int r = 0; r < 4; ++r) {
        long m = bm + wm * 64 + i * 16 + q4 * 4 + r;
        #pragma unroll
        for (int jj = 0; jj < 2; ++jj) {
          float gt = acc[i][2 * jj][r];
          float up = acc[i][2 * jj + 1][r];
          float u = 0.7978845608f * (gt + 0.044715f * gt * gt * gt);
          float e = __builtin_amdgcn_exp2f(u * 2.8853900817779268f);
          float gl = gt * (1.0f - __builtin_amdgcn_rcpf(e + 1.0f));
          long a = (bn >> 1) + wn * 32 + jj * 16 + l15;
          C[m * ldc + a] = f2bf(gl * up);
        }
      }
  }
}

// ---------------- GEMM: 256x256 8-phase schedule (T2+T3+T4+T5) ----------------
// EPI 0: fp32 C.  EPI 1: gate/up gelu pairing -> bf16.
// EPI 2: fused qkv epilogue — per-256-col block == one head:
//        nb<8: RoPE -> Qr ; nb in 8..11: RoPE -> Kr ; nb>=12: transpose -> VT.
template <int EPI>
__global__ __launch_bounds__(512, 2)
void gemm8(const __bf16* __restrict__ A, const __bf16* __restrict__ B,
           void* __restrict__ Cout, int K, int ldc,
           const int* __restrict__ positions,
           __bf16* __restrict__ QrO, __bf16* __restrict__ KrO,
           __bf16* __restrict__ VTO) {
  __shared__ __bf16 smemb[65536];    // 128KiB: A dbuf [0,32768), B dbuf [32768,65536)
  __bf16* Asmem = smemb;
  __bf16* Bsmem = smemb + 32768;
  const __bf16* Asb = Asmem;
  const __bf16* Bsb = Bsmem;

  int tid = threadIdx.x;            // 0..511
  int wave = tid >> 6, lane = tid & 63;
  int wm = wave >> 2;               // 0..1
  int wn = wave & 3;                // 0..3
  int q4 = lane >> 4, l15 = lane & 15;
  int xk = l15 & 7;

  int nwgx = gridDim.x;
  int nwg = nwgx * gridDim.y;
  int orig = blockIdx.y * nwgx + blockIdx.x;
  int qd = nwg >> 3, rm = nwg & 7;
  int xcd = orig & 7, idx = orig >> 3;
  int swz = (xcd < rm ? xcd * (qd + 1) : rm * (qd + 1) + (xcd - rm) * qd) + idx;
  long bm = (long)(swz / nwgx) * 256;
  long bn = (long)(swz % nwgx) * 256;

  int rr = tid >> 3;                 // 0..63
  int cs = (tid & 7) ^ (rr & 7);
  const __bf16* Ag = A + (bm + rr) * (long)K + cs * 8;
  const __bf16* Bg = B + (bn + rr) * (long)K + cs * 8;
  __bf16* Asd = Asmem + tid * 8;
  __bf16* Bsd = Bsmem + tid * 8;

#define ST_A(buf, h, kof) do { \
    g2l16(Ag + ((h) * 128LL      ) * K + (kof), Asd + (buf) * 16384 + (h) * 8192); \
    g2l16(Ag + ((h) * 128LL + 64 ) * K + (kof), Asd + (buf) * 16384 + (h) * 8192 + 4096); } while (0)
#define ST_B(buf, h, kof) do { \
    g2l16(Bg + ((h) * 128LL      ) * K + (kof), Bsd + (buf) * 16384 + (h) * 8192); \
    g2l16(Bg + ((h) * 128LL + 64 ) * K + (kof), Bsd + (buf) * 16384 + (h) * 8192 + 4096); } while (0)

  int aOff[4], bOff[4];
  #pragma unroll
  for (int i = 0; i < 4; ++i) {
    aOff[i] = (wm * 64 + i * 16 + l15) * 64;
    bOff[i] = (wn * 64 + i * 16 + l15) * 64;
  }

#define PH_LOAD_A(buf, mh, ks) \
  { _Pragma("unroll") for (int f = 0; f < 4; ++f) \
      afr[f] = *(const bf16x8*)(Asb + (buf) * 16384 + (mh) * 8192 + aOff[f] + ((((ks) * 4 + q4) ^ xk) * 8)); }
#define PH_LOAD_B(buf) \
  { _Pragma("unroll") for (int ks2 = 0; ks2 < 2; ++ks2) \
    _Pragma("unroll") for (int j = 0; j < 4; ++j) \
      bfr[ks2][j] = *(const bf16x8*)(Bsb + (buf) * 16384 + bOff[j] + (((ks2 * 4 + q4) ^ xk) * 8)); }
#define PH_CORE(mh, ks) \
  __builtin_amdgcn_s_barrier(); \
  asm volatile("s_waitcnt lgkmcnt(0)" ::: "memory"); \
  __builtin_amdgcn_s_setprio(1); \
  { _Pragma("unroll") for (int f = 0; f < 4; ++f) \
    _Pragma("unroll") for (int j = 0; j < 4; ++j) \
      acc[(mh) * 4 + f][j] = __builtin_amdgcn_mfma_f32_16x16x32_bf16(afr[f], bfr[ks][j], acc[(mh) * 4 + f][j], 0, 0, 0); } \
  __builtin_amdgcn_s_setprio(0)
#define BAR   __builtin_amdgcn_s_barrier()
#define WVM6  asm volatile("s_waitcnt vmcnt(6)" ::: "memory")
#define WVM0  asm volatile("s_waitcnt vmcnt(0)" ::: "memory")

  f32x4 acc[8][4] = {};
  bf16x8 bfr[2][4];
  bf16x8 afr[4];

  int nt = K >> 6;                   // K-tiles (even, >= 4)
  int nit = (nt >> 1) - 1;           // main-loop iterations (pairs of tiles)

  ST_B(0, 0, 0); ST_B(0, 1, 0); ST_A(0, 0, 0); ST_A(0, 1, 0);
  ST_B(1, 0, 64); ST_B(1, 1, 64); ST_A(1, 0, 64);
  WVM6;
  BAR;

  for (int it = 0; it < nit; ++it) {
    const long k0 = (long)it * 128;
    PH_LOAD_B(0); PH_LOAD_A(0, 0, 0); ST_A(1, 1, k0 + 64);
    asm volatile("s_waitcnt lgkmcnt(8)" ::: "memory");
    PH_CORE(0, 0); BAR;
    PH_LOAD_A(0, 0, 1); ST_B(0, 0, k0 + 128);
    PH_CORE(0, 1); BAR;
    PH_LOAD_A(0, 1, 0); ST_B(0, 1, k0 + 128);
    PH_CORE(1, 0); BAR;
    PH_LOAD_A(0, 1, 1); ST_A(0, 0, k0 + 128);
    PH_CORE(1, 1); WVM6; BAR;
    PH_LOAD_B(1); PH_LOAD_A(1, 0, 0); ST_A(0, 1, k0 + 128);
    asm volatile("s_waitcnt lgkmcnt(8)" ::: "memory");
    PH_CORE(0, 0); BAR;
    PH_LOAD_A(1, 0, 1); ST_B(1, 0, k0 + 192);
    PH_CORE(0, 1); BAR;
    PH_LOAD_A(1, 1, 0); ST_B(1, 1, k0 + 192);
    PH_CORE(1, 0); BAR;
    PH_LOAD_A(1, 1, 1); ST_A(1, 0, k0 + 192);
    PH_CORE(1, 1); WVM6; BAR;
  }

  {
    const long k0 = (long)(nt - 2) * 64;
    PH_LOAD_B(0); PH_LOAD_A(0, 0, 0); ST_A(1, 1, k0 + 64);
    asm volatile("s_waitcnt lgkmcnt(8)" ::: "memory");
    PH_CORE(0, 0); BAR;
    PH_LOAD_A(0, 0, 1); PH_CORE(0, 1); BAR;
    PH_LOAD_A(0, 1, 0); PH_CORE(1, 0); BAR;
    PH_LOAD_A(0, 1, 1); PH_CORE(1, 1); WVM0; BAR;
    PH_LOAD_B(1); PH_LOAD_A(1, 0, 0); PH_CORE(0, 0); BAR;
    PH_LOAD_A(1, 0, 1); PH_CORE(0, 1); BAR;
    PH_LOAD_A(1, 1, 0); PH_CORE(1, 0); BAR;
    PH_LOAD_A(1, 1, 1); PH_CORE(1, 1);
  }

#undef ST_A
#undef ST_B
#undef PH_LOAD_A
#undef PH_LOAD_B
#undef PH_CORE
#undef BAR
#undef WVM6
#undef WVM0

  if (EPI == 0) {
    float* C = (float*)Cout;
    #pragma unroll
    for (int mi = 0; mi < 8; ++mi) {
      int mh = mi >> 2, f = mi & 3;
      #pragma unroll
      for (int r = 0; r < 4; ++r) {
        long m = bm + mh * 128 + wm * 64 + f * 16 + q4 * 4 + r;
        #pragma unroll
        for (int j = 0; j < 4; ++j)
          C[m * ldc + bn + wn * 64 + j * 16 + l15] = acc[mi][j][r];
      }
    }
  } else if (EPI == 1) {
    __bf16* C = (__bf16*)Cout;
    #pragma unroll
    for (int mi = 0; mi < 8; ++mi) {
      int mh = mi >> 2, f = mi & 3;
      #pragma unroll
      for (int r = 0; r < 4; ++r) {
        long m = bm + mh * 128 + wm * 64 + f * 16 + q4 * 4 + r;
        #pragma unroll
        for (int jj = 0; jj < 2; ++jj) {
          float gt = acc[mi][2 * jj][r];
          float up = acc[mi][2 * jj + 1][r];
          float u = 0.7978845608f * (gt + 0.044715f * gt * gt * gt);
          float e = __builtin_amdgcn_exp2f(u * 2.8853900817779268f);
          float gl = gt * (1.0f - __builtin_amdgcn_rcpf(e + 1.0f));
          long a = (bn >> 1) + (wn >> 1) * 64 + (wn & 1) * 32 + jj * 16 + l15;
          C[m * ldc + a] = f2bf(gl * up);
        }
      }
    }
  } else {
    // fused qkv epilogue. nb = head-block index (block-uniform).
    int nb = (int)(bn >> 8);
    if (nb >= 12) {
      // v head: VT[hv*256 + c][m] transpose write, 4 rows packed per store.
      int hv = nb - 12;
      #pragma unroll
      for (int mi = 0; mi < 8; ++mi) {
        int mh = mi >> 2, f = mi & 3;
        long m0 = bm + mh * 128 + wm * 64 + f * 16 + q4 * 4;
        #pragma unroll
        for (int j = 0; j < 4; ++j) {
          int c = wn * 64 + j * 16 + l15;
          bf16x4 pk;
          #pragma unroll
          for (int r = 0; r < 4; ++r) pk[r] = f2bf(acc[mi][j][r]);
          *(bf16x4*)(VTO + (long)(hv * 256 + c) * S_LEN + m0) = pk;
        }
      }
    } else {
      // q/k head: RoPE. Pair (d, d+128) lives in waves (wn, wn+2): exchange
      // the upper half through LDS (reusing smemb), 128-row (mh) passes.
      float* Lf = (float*)smemb;        // [128][132] floats = 67.6 KB
      bool isQ = nb < 8;
      __bf16* Op = isQ ? QrO : KrO;
      long rstride = isQ ? QH : KVH;
      int hh = isQ ? nb : nb - 8;
      const float LOG_TH_128 = 0.07195578415294675f;   // ln(10000)/128
      #pragma unroll
      for (int mh = 0; mh < 2; ++mh) {
        __syncthreads();                // Lf free (main loop / prev pass done)
        if (wn >= 2) {
          #pragma unroll
          for (int f = 0; f < 4; ++f) {
            int row = wm * 64 + f * 16 + q4 * 4;
            #pragma unroll
            for (int j = 0; j < 4; ++j) {
              int d = (wn - 2) * 64 + j * 16 + l15;
              #pragma unroll
              for (int r = 0; r < 4; ++r)
                Lf[(row + r) * 132 + d] = acc[mh * 4 + f][j][r];
            }
          }
        }
        __syncthreads();
        if (wn < 2) {
          #pragma unroll
          for (int f = 0; f < 4; ++f) {
            #pragma unroll
            for (int r = 0; r < 4; ++r) {
              int rl = wm * 64 + f * 16 + q4 * 4 + r;
              long m = bm + mh * 128 + rl;
              float pos = (float)positions[m];
              #pragma unroll
              for (int j = 0; j < 4; ++j) {
                int d = wn * 64 + j * 16 + l15;
                float x1 = acc[mh * 4 + f][j][r];
                float x2 = Lf[rl * 132 + d];
                float fr = pos * expf(-(float)d * LOG_TH_128);
                float sn, cc; sincosf(fr, &sn, &cc);
                __bf16* op = Op + m * rstride + hh * 256 + d;
                op[0]   = f2bf(x1 * cc - x2 * sn);
                op[128] = f2bf(x2 * cc + x1 * sn);
              }
            }
          }
        }
      }
    }
  }
}

// ---------------- flash attention, sliding window 1024, softcap 50 ------------
// 8 waves / 128 q-rows per block, grid 32x8 = 256 blocks (1/CU).
// Double-buffered K/V staging with counted vmcnt(8) (no per-tile drain).
__global__ __launch_bounds__(512, 1)
void attn_kernel(const __bf16* __restrict__ Qr, const __bf16* __restrict__ Kr,
                 const __bf16* __restrict__ VT, __bf16* __restrict__ AT) {
  __shared__ __bf16 Kt[2][64 * 256];   // [key][d], chunk slot = c ^ (key&7)
  __shared__ __bf16 Vt[2][256 * 64];   // [d][key], chunk slot = c ^ (d&7)
  __shared__ __bf16 Pt[8][16 * 72];    // per-wave P relayout, row stride 72
  int tid = threadIdx.x, wave = tid >> 6, lane = tid & 63;
  int q4 = lane >> 4, l15 = lane & 15;
  int h = blockIdx.y, hk = h >> 1;
  int qb = blockIdx.x * 128;
  int wqb = qb + wave * 16;

  bf16x8 qf[8];
  {
    const __bf16* qp = Qr + (long)(wqb + l15) * QH + h * HDIM + q4 * 8;
    #pragma unroll
    for (int ks = 0; ks < 8; ++ks) qf[ks] = *(const bf16x8*)(qp + ks * 32);
  }
  f32x4 Oa[16] = {};
  float lsum[4] = {0.f, 0.f, 0.f, 0.f};

  // staging (512 threads): K rows (tid>>5)+16l l=0..3; V rows (tid>>3)+64l.
  // Row-step multiples of 16/64 preserve row&7 -> XOR chunk swizzle invariant.
  int csk = (tid & 31) ^ ((tid >> 5) & 7);
  const __bf16* Kh = Kr + (long)(tid >> 5) * KVH + hk * HDIM + csk * 8;
  int csv = (tid & 7) ^ ((tid >> 3) & 7);
  const __bf16* Vh = VT + (long)(hk * HDIM + (tid >> 3)) * S_LEN + csv * 8;

  int lo = qb - 1023; if (lo < 0) lo = 0;
  int t0 = lo >> 6, t1 = (qb + 127) >> 6;

#define STAGE(t, b) do { \
    int k0s = (t) * 64; \
    _Pragma("unroll") \
    for (int l = 0; l < 4; ++l) { \
      g2l16(Kh + ((long)k0s + l * 16) * KVH, &Kt[(b)][tid * 8 + l * 4096]); \
      g2l16(Vh + k0s + (long)(l * 64) * S_LEN, &Vt[(b)][tid * 8 + l * 4096]); \
    } } while (0)

  STAGE(t0, 0);
  asm volatile("s_waitcnt vmcnt(0)" ::: "memory");
  __builtin_amdgcn_s_barrier();

  for (int t = t0; t <= t1; ++t) {
    int b = (t - t0) & 1;
    if (t < t1) {
      STAGE(t + 1, b ^ 1);
      asm volatile("s_waitcnt vmcnt(8)" ::: "memory");
    } else {
      asm volatile("s_waitcnt vmcnt(0)" ::: "memory");
    }
    __builtin_amdgcn_s_barrier();     // all waves' tile-t loads complete
    int k0 = t * 64;
    bool active = (k0 <= wqb + 15) && (k0 + 63 >= wqb - 1023);
    if (active) {
      f32x4 Sa[4] = {};
      #pragma unroll
      for (int ks = 0; ks < 8; ++ks)
        #pragma unroll
        for (int j = 0; j < 4; ++j) {
          int key = j * 16 + l15;
          int cc = (ks * 4 + q4) ^ (l15 & 7);       // key&7 == l15&7
          bf16x8 kf = *(const bf16x8*)(&Kt[b][key * 256 + cc * 8]);
          Sa[j] = __builtin_amdgcn_mfma_f32_16x16x32_bf16(qf[ks], kf, Sa[j], 0, 0, 0);
        }
      #pragma unroll
      for (int r = 0; r < 4; ++r) {
        int qi = wqb + q4 * 4 + r;
        #pragma unroll
        for (int j = 0; j < 4; ++j) {
          int kj = k0 + j * 16 + l15;
          float y = Sa[j][r] * 1.25e-3f;            // * SCALE(1/16) / 50
          float e = __builtin_amdgcn_exp2f(y * 2.8853900817779268f);
          float p = __builtin_amdgcn_exp2f(72.13475204444817f
                     - 144.26950408889634f * __builtin_amdgcn_rcpf(e + 1.0f));
          bool ok = (kj <= qi) && (qi - kj < 1024);
          p = ok ? p : 0.0f;
          lsum[r] += p;
          Pt[wave][(q4 * 4 + r) * 72 + j * 16 + l15] = f2bf(p);
        }
      }
      asm volatile("s_waitcnt lgkmcnt(0)" ::: "memory");
      bf16x8 pf[2];
      #pragma unroll
      for (int ks = 0; ks < 2; ++ks)
        pf[ks] = *(const bf16x8*)(&Pt[wave][l15 * 72 + ks * 32 + q4 * 8]);
      #pragma unroll
      for (int f = 0; f < 16; ++f) {
        int d = f * 16 + l15;
        #pragma unroll
        for (int ks = 0; ks < 2; ++ks) {
          int cc = (ks * 4 + q4) ^ (l15 & 7);       // d&7 == l15&7
          bf16x8 vf = *(const bf16x8*)(&Vt[b][d * 64 + cc * 8]);
          Oa[f] = __builtin_amdgcn_mfma_f32_16x16x32_bf16(pf[ks], vf, Oa[f], 0, 0, 0);
        }
      }
    }
    __builtin_amdgcn_s_barrier();     // buf b fully consumed -> next STAGE may overwrite
  }
#undef STAGE

  #pragma unroll
  for (int r = 0; r < 4; ++r) {
    float v = lsum[r];
    #pragma unroll
    for (int o = 1; o < 16; o <<= 1) v += __shfl_xor(v, o);
    lsum[r] = __builtin_amdgcn_rcpf(v);
  }
  #pragma unroll
  for (int f = 0; f < 16; ++f)
    #pragma unroll
    for (int r = 0; r < 4; ++r) {
      long qi = wqb + q4 * 4 + r;
      AT[qi * QH + h * HDIM + f * 16 + l15] = f2bf(Oa[f][r] * lsum[r]);
    }
}

// ---------------- launch ------------------------------------------------------
extern "C" void kernel_launch(void* const* d_in, const int* in_sizes, int n_in,
                              void* d_out, int out_size, void* d_ws, size_t ws_size,
                              hipStream_t stream) {
  (void)in_sizes; (void)n_in; (void)out_size; (void)ws_size;
  const int*   positions = (const int*)d_in[0];
  const float* hidden    = (const float*)d_in[1];
  const float* w_qkv     = (const float*)d_in[2];
  const float* w_o       = (const float*)d_in[3];
  const float* w_gu      = (const float*)d_in[4];
  const float* w_dn      = (const float*)d_in[5];
  const float* w_in_ln   = (const float*)d_in[6];
  const float* w_post    = (const float*)d_in[7];
  const float* w_pre     = (const float*)d_in[8];
  const float* w_pff     = (const float*)d_in[9];
  float* out_h   = (float*)d_out;
  float* out_res = out_h + (size_t)S_LEN * H_DIM;

  char* p = (char*)d_ws;
  auto take = [&](size_t b) { char* r = p; p += (b + 255) & ~(size_t)255; return r; };
  __bf16* Wqkv = (__bf16*)take((size_t)QKV_N * H_DIM * 2);
  __bf16* Wo   = (__bf16*)take((size_t)H_DIM * QH * 2);
  __bf16* Wgu  = (__bf16*)take((size_t)2 * INTER * H_DIM * 2);
  __bf16* Wdn  = (__bf16*)take((size_t)H_DIM * INTER * 2);
  __bf16* Xn   = (__bf16*)take((size_t)S_LEN * H_DIM * 2);
  char*   Rbig = take((size_t)S_LEN * INTER * 2);
  __bf16* Qrb  = (__bf16*)take((size_t)S_LEN * QH * 2);
  __bf16* Krb  = (__bf16*)take((size_t)S_LEN * KVH * 2);
  __bf16* VTb  = (__bf16*)take((size_t)KVH * S_LEN * 2);
  __bf16* ATb  = (__bf16*)take((size_t)S_LEN * QH * 2);
  float*  Pf   = (float*)take((size_t)S_LEN * H_DIM * 4);
  __bf16* X2   = (__bf16*)take((size_t)S_LEN * H_DIM * 2);
  __bf16* ACT  = (__bf16*)Rbig;
  float*  Mbuf = Pf;

  dim3 blk(256);
  conv_t64<<<dim3(QKV_N / 64, H_DIM / 64), blk, 0, stream>>>(w_qkv, Wqkv, QKV_N, H_DIM);
  conv_t64<<<dim3(H_DIM / 64, QH / 64),    blk, 0, stream>>>(w_o,   Wo,   H_DIM, QH);
  conv_gu64<<<dim3(2 * INTER / 64, H_DIM / 64), blk, 0, stream>>>(w_gu, Wgu);
  conv_t64<<<dim3(H_DIM / 64, INTER / 64), blk, 0, stream>>>(w_dn,  Wdn,  H_DIM, INTER);
  rms_in_kernel<<<S_LEN, blk, 0, stream>>>(hidden, w_in_ln, Xn);
  gemm8<2><<<dim3(QKV_N / 256, S_LEN / 256), dim3(512), 0, stream>>>(
      Xn, Wqkv, nullptr, H_DIM, QKV_N, positions, Qrb, Krb, VTb);
  attn_kernel<<<dim3(S_LEN / 128, NQH), dim3(512), 0, stream>>>(Qrb, Krb, VTb, ATb);
  gemm_bt<0><<<dim3(H_DIM / 128, S_LEN / 128), blk, 0, stream>>>(ATb, Wo, Pf, QH, H_DIM);
  rms_post_attn_kernel<<<S_LEN, blk, 0, stream>>>(Pf, hidden, w_post, w_pre, out_res, X2);
  gemm8<1><<<dim3(2 * INTER / 256, S_LEN / 256), dim3(512), 0, stream>>>(
      X2, Wgu, ACT, H_DIM, INTER, nullptr, nullptr, nullptr, nullptr);
  gemm_bt<0><<<dim3(H_DIM / 128, S_LEN / 128), blk, 0, stream>>>(ACT, Wdn, Mbuf, INTER, H_DIM);
  rms_final_kernel<<<S_LEN, blk, 0, stream>>>(Mbuf, w_pff, out_h);
}

// Round 4
// 1181.021 us; speedup vs baseline: 1.1134x; 1.1134x over previous
//
#include <hip/hip_runtime.h>
#include <cstdint>
#include <cmath>

#define S_LEN 4096
#define H_DIM 2304
#define NQH   8
#define NKVH  4
#define HDIM  256
#define INTER 9216
#define QKV_N 4096   // (NQ + 2*NKV) * HD
#define QH    2048   // NQ*HD
#define KVH   1024   // NKV*HD

typedef __attribute__((ext_vector_type(4))) float  f32x4;
typedef __attribute__((ext_vector_type(8))) __bf16 bf16x8;

__device__ __forceinline__ __bf16 f2bf(float f) {
  union { float f; unsigned u; } x; x.f = f;
  unsigned r = (x.u + 0x7fffu + ((x.u >> 16) & 1u)) >> 16;   // RNE
  union { unsigned short s; __bf16 b; } y; y.s = (unsigned short)r;
  return y.b;
}

// async global->LDS, 16B per lane. LDS dest must be wave-uniform base + lane*16.
__device__ __forceinline__ void g2l16(const void* g, void* l) {
  __builtin_amdgcn_global_load_lds(
      (__attribute__((address_space(1))) void*)(uintptr_t)g,
      (__attribute__((address_space(3))) void*)(uint32_t)(uintptr_t)l, 16, 0, 0);
}

__device__ __forceinline__ float block_sum(float v, float* sbuf) {
  #pragma unroll
  for (int o = 32; o > 0; o >>= 1) v += __shfl_xor(v, o);
  __syncthreads();
  if ((threadIdx.x & 63) == 0) sbuf[threadIdx.x >> 6] = v;
  __syncthreads();
  return sbuf[0] + sbuf[1] + sbuf[2] + sbuf[3];
}

// ------------- vectorized transpose: fp32 [K][N] -> bf16 [N][K] (64x64) -------
__global__ void conv_t64(const float* __restrict__ src, __bf16* __restrict__ dst,
                         int srcStride, int dstStride) {
  __shared__ float t[64 * 65];
  int tid = threadIdx.x;                 // 256
  long n0 = (long)blockIdx.x * 64, k0 = (long)blockIdx.y * 64;
  int tx = tid & 15;                     // 16 x f32x4 = 64 floats per row
  int ky = tid >> 4;                     // 0..15
  #pragma unroll
  for (int l = 0; l < 4; ++l) {
    int k = ky + l * 16;
    f32x4 v = *(const f32x4*)(src + (k0 + k) * srcStride + n0 + tx * 4);
    #pragma unroll
    for (int e = 0; e < 4; ++e) t[(tx * 4 + e) * 65 + k] = v[e];
  }
  __syncthreads();
  int ny = tid >> 2, kc = (tid & 3) * 16;
  bf16x8 a, b;
  #pragma unroll
  for (int i = 0; i < 8; ++i) a[i] = f2bf(t[ny * 65 + kc + i]);
  #pragma unroll
  for (int i = 0; i < 8; ++i) b[i] = f2bf(t[ny * 65 + kc + 8 + i]);
  __bf16* d = dst + (n0 + ny) * dstStride + k0 + kc;
  *(bf16x8*)d = a;
  *(bf16x8*)(d + 8) = b;
}

// gate/up interleave permutation (epilogue pairing of gemm8<1>)
__device__ __forceinline__ int gu_map(int n) {
  int t = n >> 7, w = (n >> 6) & 1, j = (n >> 4) & 3, c = n & 15;
  int a = t * 64 + w * 32 + ((j >> 1) << 4) + c;
  return (j & 1) ? (INTER + a) : a;
}

__global__ void conv_gu64(const float* __restrict__ src, __bf16* __restrict__ dst) {
  __shared__ float t[64 * 65];
  int tid = threadIdx.x;
  long n0 = (long)blockIdx.x * 64, k0 = (long)blockIdx.y * 64;
  int tx = tid & 15, ky = tid >> 4;
  int sc = gu_map((int)n0 + tx * 4);
  #pragma unroll
  for (int l = 0; l < 4; ++l) {
    int k = ky + l * 16;
    f32x4 v = *(const f32x4*)(src + (k0 + k) * (2 * INTER) + sc);
    #pragma unroll
    for (int e = 0; e < 4; ++e) t[(tx * 4 + e) * 65 + k] = v[e];
  }
  __syncthreads();
  int ny = tid >> 2, kc = (tid & 3) * 16;
  bf16x8 a, b;
  #pragma unroll
  for (int i = 0; i < 8; ++i) a[i] = f2bf(t[ny * 65 + kc + i]);
  #pragma unroll
  for (int i = 0; i < 8; ++i) b[i] = f2bf(t[ny * 65 + kc + 8 + i]);
  __bf16* d = dst + (n0 + ny) * H_DIM + k0 + kc;
  *(bf16x8*)d = a;
  *(bf16x8*)(d + 8) = b;
}

// ---------------- rmsnorm kernels (H = 2304 = 9*256) --------------------------
__global__ void rms_in_kernel(const float* __restrict__ x, const float* __restrict__ w,
                              __bf16* __restrict__ out) {
  __shared__ float sbuf[4];
  int row = blockIdx.x, tid = threadIdx.x;
  const float* xr = x + (long)row * H_DIM;
  float v[9]; float ss = 0.f;
  #pragma unroll
  for (int i = 0; i < 9; ++i) { v[i] = xr[tid + i * 256]; ss += v[i] * v[i]; }
  ss = block_sum(ss, sbuf);
  float inv = rsqrtf(ss * (1.0f / H_DIM) + 1e-6f);
  #pragma unroll
  for (int i = 0; i < 9; ++i)
    out[(long)row * H_DIM + tid + i * 256] = f2bf(v[i] * inv * (1.f + w[tid + i * 256]));
}

__global__ void rms_post_attn_kernel(const float* __restrict__ P, const float* __restrict__ hidden,
                                     const float* __restrict__ w_post, const float* __restrict__ w_pre,
                                     float* __restrict__ resid, __bf16* __restrict__ x2) {
  __shared__ float sbuf[4];
  int row = blockIdx.x, tid = threadIdx.x;
  const float* pr = P + (long)row * H_DIM;
  const float* hr = hidden + (long)row * H_DIM;
  float pv[9]; float ss = 0.f;
  #pragma unroll
  for (int i = 0; i < 9; ++i) { pv[i] = pr[tid + i * 256]; ss += pv[i] * pv[i]; }
  ss = block_sum(ss, sbuf);
  float inv = rsqrtf(ss * (1.0f / H_DIM) + 1e-6f);
  float rv[9]; float ss2 = 0.f;
  #pragma unroll
  for (int i = 0; i < 9; ++i) {
    int c = tid + i * 256;
    float hn = pv[i] * inv * (1.f + w_post[c]);
    rv[i] = hn + hr[c];
    resid[(long)row * H_DIM + c] = rv[i];
    ss2 += rv[i] * rv[i];
  }
  ss2 = block_sum(ss2, sbuf);
  float inv2 = rsqrtf(ss2 * (1.0f / H_DIM) + 1e-6f);
  #pragma unroll
  for (int i = 0; i < 9; ++i) {
    int c = tid + i * 256;
    x2[(long)row * H_DIM + c] = f2bf(rv[i] * inv2 * (1.f + w_pre[c]));
  }
}

__global__ void rms_final_kernel(const float* __restrict__ x, const float* __restrict__ w,
                                 float* __restrict__ out) {
  __shared__ float sbuf[4];
  int row = blockIdx.x, tid = threadIdx.x;
  const float* xr = x + (long)row * H_DIM;
  float v[9]; float ss = 0.f;
  #pragma unroll
  for (int i = 0; i < 9; ++i) { v[i] = xr[tid + i * 256]; ss += v[i] * v[i]; }
  ss = block_sum(ss, sbuf);
  float inv = rsqrtf(ss * (1.0f / H_DIM) + 1e-6f);
  #pragma unroll
  for (int i = 0; i < 9; ++i)
    out[(long)row * H_DIM + tid + i * 256] = v[i] * inv * (1.f + w[tid + i * 256]);
}

// ---------------- RoPE: qkv fp32 -> Qr/Kr bf16 (vectorized) -------------------
__global__ void rope_kernel(const float* __restrict__ qkv, const int* __restrict__ positions,
                            __bf16* __restrict__ Qr, __bf16* __restrict__ Kr) {
  int row = blockIdx.x, tid = threadIdx.x;
  float pos = (float)positions[row];
  const float LOG_TH_128 = 9.210340371976184f / 128.f;  // ln(10000)/128
  bool isQ = tid < 128;
  int c = isQ ? tid : (tid - 128);
  int hh = c >> 4;            // head index within group
  int d0 = (c & 15) * 8;      // 0..120
  const float* base = qkv + (long)row * QKV_N + (isQ ? 0 : QH) + hh * 256;
  f32x4 x1a = *(const f32x4*)(base + d0);
  f32x4 x1b = *(const f32x4*)(base + d0 + 4);
  f32x4 x2a = *(const f32x4*)(base + d0 + 128);
  f32x4 x2b = *(const f32x4*)(base + d0 + 132);
  bf16x8 lo, hi;
  #pragma unroll
  for (int j = 0; j < 8; ++j) {
    float x1 = j < 4 ? x1a[j] : x1b[j - 4];
    float x2 = j < 4 ? x2a[j] : x2b[j - 4];
    float fr = pos * expf(-(float)(d0 + j) * LOG_TH_128);
    float sn, cs; sincosf(fr, &sn, &cs);
    lo[j] = f2bf(x1 * cs - x2 * sn);
    hi[j] = f2bf(x2 * cs + x1 * sn);
  }
  __bf16* out = (isQ ? Qr + (long)row * QH : Kr + (long)row * KVH) + hh * 256;
  *(bf16x8*)(out + d0) = lo;
  *(bf16x8*)(out + 128 + d0) = hi;
}

// ---------------- GEMM: C[M][N] = A[M][K](bf16) x B[N][K](bf16) ---------------
// 128x128 tile, 4 waves 2x2, BK=64, global_load_lds width 16, XOR chunk swizzle,
// bijective XCD swizzle. Used for Wo and down GEMMs.
template <int EPI>
__global__ void gemm_bt(const __bf16* __restrict__ A, const __bf16* __restrict__ B,
                        void* __restrict__ Cout, int K, int ldc) {
  __shared__ __bf16 As[128 * 64];
  __shared__ __bf16 Bs[128 * 64];
  int tid = threadIdx.x;
  int wave = tid >> 6, lane = tid & 63;
  int wm = wave >> 1, wn = wave & 1;
  int q4 = lane >> 4, l15 = lane & 15;

  int nwgx = gridDim.x;
  int nwg = nwgx * gridDim.y;
  int orig = blockIdx.y * nwgx + blockIdx.x;
  int qd = nwg >> 3, rm = nwg & 7;
  int xcd = orig & 7, idx = orig >> 3;
  int swz = (xcd < rm ? xcd * (qd + 1) : rm * (qd + 1) + (xcd - rm) * qd) + idx;
  long bm = (long)(swz / nwgx) * 128, bn = (long)(swz % nwgx) * 128;

  int r8 = tid >> 3;                         // 0..31
  int cs = (tid & 7) ^ (r8 & 7);
  const __bf16* Ag = A + (bm + r8) * K + cs * 8;
  const __bf16* Bg = B + (bn + r8) * K + cs * 8;
  __bf16* Asd = As + tid * 8;
  __bf16* Bsd = Bs + tid * 8;

  int moff[4], noff[4];
  #pragma unroll
  for (int i = 0; i < 4; ++i) {
    moff[i] = (wm * 64 + i * 16 + l15) * 64;
    noff[i] = (wn * 64 + i * 16 + l15) * 64;
  }
  int c0 = (q4 ^ (l15 & 7)) * 8;             // ks=0 element offset; ks=1: ^32
  f32x4 acc[4][4] = {};

  for (int k0 = 0; k0 < K; k0 += 64) {
    #pragma unroll
    for (int l = 0; l < 4; ++l) {
      g2l16(Ag + (long)(l * 32) * K, Asd + l * 2048);
      g2l16(Bg + (long)(l * 32) * K, Bsd + l * 2048);
    }
    Ag += 64; Bg += 64;
    __syncthreads();
    #pragma unroll
    for (int ks = 0; ks < 2; ++ks) {
      int cc = c0 ^ (ks * 32);
      bf16x8 af[4], bfv[4];
      #pragma unroll
      for (int i = 0; i < 4; ++i) af[i]  = *(const bf16x8*)(As + moff[i] + cc);
      #pragma unroll
      for (int j = 0; j < 4; ++j) bfv[j] = *(const bf16x8*)(Bs + noff[j] + cc);
      #pragma unroll
      for (int i = 0; i < 4; ++i)
        #pragma unroll
        for (int j = 0; j < 4; ++j)
          acc[i][j] = __builtin_amdgcn_mfma_f32_16x16x32_bf16(af[i], bfv[j], acc[i][j], 0, 0, 0);
    }
    __syncthreads();
  }

  if (EPI == 0) {
    float* C = (float*)Cout;
    #pragma unroll
    for (int i = 0; i < 4; ++i)
      #pragma unroll
      for (int r = 0; r < 4; ++r) {
        long m = bm + wm * 64 + i * 16 + q4 * 4 + r;
        #pragma unroll
        for (int j = 0; j < 4; ++j)
          C[m * ldc + bn + wn * 64 + j * 16 + l15] = acc[i][j][r];
      }
  } else {
    __bf16* C = (__bf16*)Cout;
    #pragma unroll
    for (int i = 0; i < 4; ++i)
      #pragma unroll
      for (int r = 0; r < 4; ++r) {
        long m = bm + wm * 64 + i * 16 + q4 * 4 + r;
        #pragma unroll
        for (int jj = 0; jj < 2; ++jj) {
          float gt = acc[i][2 * jj][r];
          float up = acc[i][2 * jj + 1][r];
          float u = 0.7978845608f * (gt + 0.044715f * gt * gt * gt);
          float e = __builtin_amdgcn_exp2f(u * 2.8853900817779268f);
          float gl = gt * (1.0f - __builtin_amdgcn_rcpf(e + 1.0f));
          long a = (bn >> 1) + wn * 32 + jj * 16 + l15;
          C[m * ldc + a] = f2bf(gl * up);
        }
      }
  }
}

// ---------------- GEMM: 256x256 8-phase schedule (T2+T3+T4+T5) ----------------
// (exact R2 form: two LDS arrays, 6-arg signature — the R3 merge regressed it)
template <int EPI>
__global__ __launch_bounds__(512, 2)
void gemm8(const __bf16* __restrict__ A, const __bf16* __restrict__ B,
           void* __restrict__ Cout, int K, int ldc) {
  __shared__ __bf16 As[2][16384];   // [buf][256 rows x 64 k], chunk slot = c ^ (row&7)
  __shared__ __bf16 Bs[2][16384];
  const __bf16* Asb = (const __bf16*)As;
  const __bf16* Bsb = (const __bf16*)Bs;

  int tid = threadIdx.x;            // 0..511
  int wave = tid >> 6, lane = tid & 63;
  int wm = wave >> 2;               // 0..1
  int wn = wave & 3;                // 0..3
  int q4 = lane >> 4, l15 = lane & 15;
  int xk = l15 & 7;

  int nwgx = gridDim.x;
  int nwg = nwgx * gridDim.y;
  int orig = blockIdx.y * nwgx + blockIdx.x;
  int qd = nwg >> 3, rm = nwg & 7;
  int xcd = orig & 7, idx = orig >> 3;
  int swz = (xcd < rm ? xcd * (qd + 1) : rm * (qd + 1) + (xcd - rm) * qd) + idx;
  long bm = (long)(swz / nwgx) * 256;
  long bn = (long)(swz % nwgx) * 256;

  int rr = tid >> 3;                 // 0..63
  int cs = (tid & 7) ^ (rr & 7);
  const __bf16* Ag = A + (bm + rr) * (long)K + cs * 8;
  const __bf16* Bg = B + (bn + rr) * (long)K + cs * 8;
  __bf16* Asd = (__bf16*)As + tid * 8;
  __bf16* Bsd = (__bf16*)Bs + tid * 8;

#define ST_A(buf, h, kof) do { \
    g2l16(Ag + ((h) * 128LL      ) * K + (kof), Asd + (buf) * 16384 + (h) * 8192); \
    g2l16(Ag + ((h) * 128LL + 64 ) * K + (kof), Asd + (buf) * 16384 + (h) * 8192 + 4096); } while (0)
#define ST_B(buf, h, kof) do { \
    g2l16(Bg + ((h) * 128LL      ) * K + (kof), Bsd + (buf) * 16384 + (h) * 8192); \
    g2l16(Bg + ((h) * 128LL + 64 ) * K + (kof), Bsd + (buf) * 16384 + (h) * 8192 + 4096); } while (0)

  int aOff[4], bOff[4];
  #pragma unroll
  for (int i = 0; i < 4; ++i) {
    aOff[i] = (wm * 64 + i * 16 + l15) * 64;
    bOff[i] = (wn * 64 + i * 16 + l15) * 64;
  }

#define PH_LOAD_A(buf, mh, ks) \
  { _Pragma("unroll") for (int f = 0; f < 4; ++f) \
      afr[f] = *(const bf16x8*)(Asb + (buf) * 16384 + (mh) * 8192 + aOff[f] + ((((ks) * 4 + q4) ^ xk) * 8)); }
#define PH_LOAD_B(buf) \
  { _Pragma("unroll") for (int ks2 = 0; ks2 < 2; ++ks2) \
    _Pragma("unroll") for (int j = 0; j < 4; ++j) \
      bfr[ks2][j] = *(const bf16x8*)(Bsb + (buf) * 16384 + bOff[j] + (((ks2 * 4 + q4) ^ xk) * 8)); }
#define PH_CORE(mh, ks) \
  __builtin_amdgcn_s_barrier(); \
  asm volatile("s_waitcnt lgkmcnt(0)" ::: "memory"); \
  __builtin_amdgcn_s_setprio(1); \
  { _Pragma("unroll") for (int f = 0; f < 4; ++f) \
    _Pragma("unroll") for (int j = 0; j < 4; ++j) \
      acc[(mh) * 4 + f][j] = __builtin_amdgcn_mfma_f32_16x16x32_bf16(afr[f], bfr[ks][j], acc[(mh) * 4 + f][j], 0, 0, 0); } \
  __builtin_amdgcn_s_setprio(0)
#define BAR   __builtin_amdgcn_s_barrier()
#define WVM6  asm volatile("s_waitcnt vmcnt(6)" ::: "memory")
#define WVM0  asm volatile("s_waitcnt vmcnt(0)" ::: "memory")

  f32x4 acc[8][4] = {};
  bf16x8 bfr[2][4];
  bf16x8 afr[4];

  int nt = K >> 6;                   // K-tiles (even, >= 4)
  int nit = (nt >> 1) - 1;           // main-loop iterations (pairs of tiles)

  ST_B(0, 0, 0); ST_B(0, 1, 0); ST_A(0, 0, 0); ST_A(0, 1, 0);
  ST_B(1, 0, 64); ST_B(1, 1, 64); ST_A(1, 0, 64);
  WVM6;
  BAR;

  for (int it = 0; it < nit; ++it) {
    const long k0 = (long)it * 128;
    PH_LOAD_B(0); PH_LOAD_A(0, 0, 0); ST_A(1, 1, k0 + 64);
    asm volatile("s_waitcnt lgkmcnt(8)" ::: "memory");
    PH_CORE(0, 0); BAR;
    PH_LOAD_A(0, 0, 1); ST_B(0, 0, k0 + 128);
    PH_CORE(0, 1); BAR;
    PH_LOAD_A(0, 1, 0); ST_B(0, 1, k0 + 128);
    PH_CORE(1, 0); BAR;
    PH_LOAD_A(0, 1, 1); ST_A(0, 0, k0 + 128);
    PH_CORE(1, 1); WVM6; BAR;
    PH_LOAD_B(1); PH_LOAD_A(1, 0, 0); ST_A(0, 1, k0 + 128);
    asm volatile("s_waitcnt lgkmcnt(8)" ::: "memory");
    PH_CORE(0, 0); BAR;
    PH_LOAD_A(1, 0, 1); ST_B(1, 0, k0 + 192);
    PH_CORE(0, 1); BAR;
    PH_LOAD_A(1, 1, 0); ST_B(1, 1, k0 + 192);
    PH_CORE(1, 0); BAR;
    PH_LOAD_A(1, 1, 1); ST_A(1, 0, k0 + 192);
    PH_CORE(1, 1); WVM6; BAR;
  }

  {
    const long k0 = (long)(nt - 2) * 64;
    PH_LOAD_B(0); PH_LOAD_A(0, 0, 0); ST_A(1, 1, k0 + 64);
    asm volatile("s_waitcnt lgkmcnt(8)" ::: "memory");
    PH_CORE(0, 0); BAR;
    PH_LOAD_A(0, 0, 1); PH_CORE(0, 1); BAR;
    PH_LOAD_A(0, 1, 0); PH_CORE(1, 0); BAR;
    PH_LOAD_A(0, 1, 1); PH_CORE(1, 1); WVM0; BAR;
    PH_LOAD_B(1); PH_LOAD_A(1, 0, 0); PH_CORE(0, 0); BAR;
    PH_LOAD_A(1, 0, 1); PH_CORE(0, 1); BAR;
    PH_LOAD_A(1, 1, 0); PH_CORE(1, 0); BAR;
    PH_LOAD_A(1, 1, 1); PH_CORE(1, 1);
  }

#undef ST_A
#undef ST_B
#undef PH_LOAD_A
#undef PH_LOAD_B
#undef PH_CORE
#undef BAR
#undef WVM6
#undef WVM0

  if (EPI == 0) {
    float* C = (float*)Cout;
    #pragma unroll
    for (int mi = 0; mi < 8; ++mi) {
      int mh = mi >> 2, f = mi & 3;
      #pragma unroll
      for (int r = 0; r < 4; ++r) {
        long m = bm + mh * 128 + wm * 64 + f * 16 + q4 * 4 + r;
        #pragma unroll
        for (int j = 0; j < 4; ++j)
          C[m * ldc + bn + wn * 64 + j * 16 + l15] = acc[mi][j][r];
      }
    }
  } else {
    __bf16* C = (__bf16*)Cout;
    #pragma unroll
    for (int mi = 0; mi < 8; ++mi) {
      int mh = mi >> 2, f = mi & 3;
      #pragma unroll
      for (int r = 0; r < 4; ++r) {
        long m = bm + mh * 128 + wm * 64 + f * 16 + q4 * 4 + r;
        #pragma unroll
        for (int jj = 0; jj < 2; ++jj) {
          float gt = acc[mi][2 * jj][r];
          float up = acc[mi][2 * jj + 1][r];
          float u = 0.7978845608f * (gt + 0.044715f * gt * gt * gt);
          float e = __builtin_amdgcn_exp2f(u * 2.8853900817779268f);
          float gl = gt * (1.0f - __builtin_amdgcn_rcpf(e + 1.0f));
          long a = (bn >> 1) + (wn >> 1) * 64 + (wn & 1) * 32 + jj * 16 + l15;
          C[m * ldc + a] = f2bf(gl * up);
        }
      }
    }
  }
}

// ---------------- flash attention, sliding window 1024, softcap 50 ------------
// 8 waves / 128 q-rows per block, grid 32x8 = 256 blocks (1/CU).
// Double-buffered K/V staging with counted vmcnt(8) (no per-tile drain).
__global__ __launch_bounds__(512, 1)
void attn_kernel(const __bf16* __restrict__ Qr, const __bf16* __restrict__ Kr,
                 const __bf16* __restrict__ VT, __bf16* __restrict__ AT) {
  __shared__ __bf16 Kt[2][64 * 256];   // [key][d], chunk slot = c ^ (key&7)
  __shared__ __bf16 Vt[2][256 * 64];   // [d][key], chunk slot = c ^ (d&7)
  __shared__ __bf16 Pt[8][16 * 72];    // per-wave P relayout, row stride 72
  int tid = threadIdx.x, wave = tid >> 6, lane = tid & 63;
  int q4 = lane >> 4, l15 = lane & 15;
  int h = blockIdx.y, hk = h >> 1;
  int qb = blockIdx.x * 128;
  int wqb = qb + wave * 16;

  bf16x8 qf[8];
  {
    const __bf16* qp = Qr + (long)(wqb + l15) * QH + h * HDIM + q4 * 8;
    #pragma unroll
    for (int ks = 0; ks < 8; ++ks) qf[ks] = *(const bf16x8*)(qp + ks * 32);
  }
  f32x4 Oa[16] = {};
  float lsum[4] = {0.f, 0.f, 0.f, 0.f};

  // staging (512 threads): K rows (tid>>5)+16l l=0..3; V rows (tid>>3)+64l.
  // Row-step multiples of 16/64 preserve row&7 -> XOR chunk swizzle invariant.
  int csk = (tid & 31) ^ ((tid >> 5) & 7);
  const __bf16* Kh = Kr + (long)(tid >> 5) * KVH + hk * HDIM + csk * 8;
  int csv = (tid & 7) ^ ((tid >> 3) & 7);
  const __bf16* Vh = VT + (long)(hk * HDIM + (tid >> 3)) * S_LEN + csv * 8;

  int lo = qb - 1023; if (lo < 0) lo = 0;
  int t0 = lo >> 6, t1 = (qb + 127) >> 6;

#define STAGE(t, b) do { \
    int k0s = (t) * 64; \
    _Pragma("unroll") \
    for (int l = 0; l < 4; ++l) { \
      g2l16(Kh + ((long)k0s + l * 16) * KVH, &Kt[(b)][tid * 8 + l * 4096]); \
      g2l16(Vh + k0s + (long)(l * 64) * S_LEN, &Vt[(b)][tid * 8 + l * 4096]); \
    } } while (0)

  STAGE(t0, 0);
  asm volatile("s_waitcnt vmcnt(0)" ::: "memory");
  __builtin_amdgcn_s_barrier();

  for (int t = t0; t <= t1; ++t) {
    int b = (t - t0) & 1;
    if (t < t1) {
      STAGE(t + 1, b ^ 1);
      asm volatile("s_waitcnt vmcnt(8)" ::: "memory");
    } else {
      asm volatile("s_waitcnt vmcnt(0)" ::: "memory");
    }
    __builtin_amdgcn_s_barrier();     // all waves' tile-t loads complete
    int k0 = t * 64;
    bool active = (k0 <= wqb + 15) && (k0 + 63 >= wqb - 1023);
    if (active) {
      f32x4 Sa[4] = {};
      #pragma unroll
      for (int ks = 0; ks < 8; ++ks)
        #pragma unroll
        for (int j = 0; j < 4; ++j) {
          int key = j * 16 + l15;
          int cc = (ks * 4 + q4) ^ (l15 & 7);       // key&7 == l15&7
          bf16x8 kf = *(const bf16x8*)(&Kt[b][key * 256 + cc * 8]);
          Sa[j] = __builtin_amdgcn_mfma_f32_16x16x32_bf16(qf[ks], kf, Sa[j], 0, 0, 0);
        }
      #pragma unroll
      for (int r = 0; r < 4; ++r) {
        int qi = wqb + q4 * 4 + r;
        #pragma unroll
        for (int j = 0; j < 4; ++j) {
          int kj = k0 + j * 16 + l15;
          float y = Sa[j][r] * 1.25e-3f;            // * SCALE(1/16) / 50
          float e = __builtin_amdgcn_exp2f(y * 2.8853900817779268f);
          float p = __builtin_amdgcn_exp2f(72.13475204444817f
                     - 144.26950408889634f * __builtin_amdgcn_rcpf(e + 1.0f));
          bool ok = (kj <= qi) && (qi - kj < 1024);
          p = ok ? p : 0.0f;
          lsum[r] += p;
          Pt[wave][(q4 * 4 + r) * 72 + j * 16 + l15] = f2bf(p);
        }
      }
      asm volatile("s_waitcnt lgkmcnt(0)" ::: "memory");
      bf16x8 pf[2];
      #pragma unroll
      for (int ks = 0; ks < 2; ++ks)
        pf[ks] = *(const bf16x8*)(&Pt[wave][l15 * 72 + ks * 32 + q4 * 8]);
      #pragma unroll
      for (int f = 0; f < 16; ++f) {
        int d = f * 16 + l15;
        #pragma unroll
        for (int ks = 0; ks < 2; ++ks) {
          int cc = (ks * 4 + q4) ^ (l15 & 7);       // d&7 == l15&7
          bf16x8 vf = *(const bf16x8*)(&Vt[b][d * 64 + cc * 8]);
          Oa[f] = __builtin_amdgcn_mfma_f32_16x16x32_bf16(pf[ks], vf, Oa[f], 0, 0, 0);
        }
      }
    }
    __builtin_amdgcn_s_barrier();     // buf b fully consumed -> next STAGE may overwrite
  }
#undef STAGE

  #pragma unroll
  for (int r = 0; r < 4; ++r) {
    float v = lsum[r];
    #pragma unroll
    for (int o = 1; o < 16; o <<= 1) v += __shfl_xor(v, o);
    lsum[r] = __builtin_amdgcn_rcpf(v);
  }
  #pragma unroll
  for (int f = 0; f < 16; ++f)
    #pragma unroll
    for (int r = 0; r < 4; ++r) {
      long qi = wqb + q4 * 4 + r;
      AT[qi * QH + h * HDIM + f * 16 + l15] = f2bf(Oa[f][r] * lsum[r]);
    }
}

// ---------------- launch ------------------------------------------------------
extern "C" void kernel_launch(void* const* d_in, const int* in_sizes, int n_in,
                              void* d_out, int out_size, void* d_ws, size_t ws_size,
                              hipStream_t stream) {
  (void)in_sizes; (void)n_in; (void)out_size; (void)ws_size;
  const int*   positions = (const int*)d_in[0];
  const float* hidden    = (const float*)d_in[1];
  const float* w_qkv     = (const float*)d_in[2];
  const float* w_o       = (const float*)d_in[3];
  const float* w_gu      = (const float*)d_in[4];
  const float* w_dn      = (const float*)d_in[5];
  const float* w_in_ln   = (const float*)d_in[6];
  const float* w_post    = (const float*)d_in[7];
  const float* w_pre     = (const float*)d_in[8];
  const float* w_pff     = (const float*)d_in[9];
  float* out_h   = (float*)d_out;
  float* out_res = out_h + (size_t)S_LEN * H_DIM;

  char* p = (char*)d_ws;
  auto take = [&](size_t b) { char* r = p; p += (b + 255) & ~(size_t)255; return r; };
  __bf16* Wqkv = (__bf16*)take((size_t)QKV_N * H_DIM * 2);
  __bf16* Wo   = (__bf16*)take((size_t)H_DIM * QH * 2);
  __bf16* Wgu  = (__bf16*)take((size_t)2 * INTER * H_DIM * 2);
  __bf16* Wdn  = (__bf16*)take((size_t)H_DIM * INTER * 2);
  __bf16* Xn   = (__bf16*)take((size_t)S_LEN * H_DIM * 2);
  char*   Rbig = take((size_t)S_LEN * INTER * 2);
  __bf16* Qrb  = (__bf16*)take((size_t)S_LEN * QH * 2);
  __bf16* Krb  = (__bf16*)take((size_t)S_LEN * KVH * 2);
  __bf16* VTb  = (__bf16*)take((size_t)KVH * S_LEN * 2);
  __bf16* ATb  = (__bf16*)take((size_t)S_LEN * QH * 2);
  float*  Pf   = (float*)take((size_t)S_LEN * H_DIM * 4);
  __bf16* X2   = (__bf16*)take((size_t)S_LEN * H_DIM * 2);
  float*  QKV  = (float*)Rbig;
  __bf16* ACT  = (__bf16*)Rbig;
  float*  Mbuf = Pf;

  dim3 blk(256);
  conv_t64<<<dim3(QKV_N / 64, H_DIM / 64), blk, 0, stream>>>(w_qkv, Wqkv, QKV_N, H_DIM);
  conv_t64<<<dim3(H_DIM / 64, QH / 64),    blk, 0, stream>>>(w_o,   Wo,   H_DIM, QH);
  conv_gu64<<<dim3(2 * INTER / 64, H_DIM / 64), blk, 0, stream>>>(w_gu, Wgu);
  conv_t64<<<dim3(H_DIM / 64, INTER / 64), blk, 0, stream>>>(w_dn,  Wdn,  H_DIM, INTER);
  rms_in_kernel<<<S_LEN, blk, 0, stream>>>(hidden, w_in_ln, Xn);
  gemm8<0><<<dim3(QKV_N / 256, S_LEN / 256), dim3(512), 0, stream>>>(Xn, Wqkv, QKV, H_DIM, QKV_N);
  rope_kernel<<<S_LEN, dim3(192), 0, stream>>>(QKV, positions, Qrb, Krb);
  conv_t64<<<dim3(KVH / 64, S_LEN / 64), blk, 0, stream>>>(QKV + QH + KVH, VTb, QKV_N, S_LEN);
  attn_kernel<<<dim3(S_LEN / 128, NQH), dim3(512), 0, stream>>>(Qrb, Krb, VTb, ATb);
  gemm_bt<0><<<dim3(H_DIM / 128, S_LEN / 128), blk, 0, stream>>>(ATb, Wo, Pf, QH, H_DIM);
  rms_post_attn_kernel<<<S_LEN, blk, 0, stream>>>(Pf, hidden, w_post, w_pre, out_res, X2);
  gemm8<1><<<dim3(2 * INTER / 256, S_LEN / 256), dim3(512), 0, stream>>>(X2, Wgu, ACT, H_DIM, INTER);
  gemm_bt<0><<<dim3(H_DIM / 128, S_LEN / 128), blk, 0, stream>>>(ACT, Wdn, Mbuf, INTER, H_DIM);
  rms_final_kernel<<<S_LEN, blk, 0, stream>>>(Mbuf, w_pff, out_h);
}